// Round 1
// baseline (4011.871 us; speedup 1.0000x reference)
//
#include <hip/hip_runtime.h>

// Spatial correlation sampler: out[b, dh*9+dw, h, w] =
//   (1/C) * sum_c in1[b,c,h,w] * in2[b,c,h+dh-4,w+dw-4]   (zero-padded)
// B=8 C=256 H=128 W=256, patch 9x9 (RADIUS=4), fp32 in/out.
//
// Restructure vs previous version:
//  - NT=576: 9 waves/block, wave w owns dh=w  -> acc = 9*4 = 36 VGPRs (was 108,
//    which overflowed into AGPRs: VGPR_Count was 84 < 108 live accumulators).
//  - LDS halo row stride padded 40 -> 44 floats (44 mod 32 = 12: the 8 rows a
//    wave reads per ds_read_b128 hit distinct bank groups; stride 40 aliased
//    th and th+4 -> measured 5.7e7 conflict cycles).
//  - Double-buffered LDS, ONE barrier per chunk: issue next chunk's global
//    loads (float4, precomputed per-thread descriptors) BEFORE compute,
//    ds_write to the other buffer AFTER compute (T14 async-stage split).

#define RADIUS 4
#define PSZ    9
#define NP     81

#define Bdim 8
#define Cdim 256
#define Hdim 128
#define Wdim 256
#define HWs  (Hdim * Wdim)

#define TW 32
#define TH 8
#define HALO_W  40                 // used floats per halo row
#define HALO_WP 44                 // padded row stride (mod 32 = 12 -> no b128 conflicts)
#define HALO_H  16
#define CK 8                       // channels per chunk
#define NCHUNK (Cdim / CK)         // 32
#define NT 576                     // 9 waves; wave = dh
#define NSEG (CK * HALO_H * (HALO_W / 4))   // 1280 float4 segments per chunk
#define BUF_FLOATS (CK * HALO_H * HALO_WP)  // 5632 floats per buffer

__global__ __launch_bounds__(NT, 5)   // force <=102 VGPR so 2 blocks (18 waves) fit per CU
void corr81(const float* __restrict__ in1, const float* __restrict__ in2,
            float* __restrict__ out)
{
    // 2 * 8 * 16 * 44 * 4 = 45056 B; 2 blocks/CU -> 90 KB of 160 KB
    __shared__ float s2[2][CK][HALO_H][HALO_WP];

    const int tid = threadIdx.x;
    const int tw  = tid & 7;          // w-subtile: 4 floats each
    const int th  = (tid >> 3) & 7;   // row within tile
    const int dh  = tid >> 6;         // wave id = dh (0..8)

    const int w0 = blockIdx.x * TW;
    const int h0 = blockIdx.y * TH;
    const int b  = blockIdx.z;

    const int hh = h0 + th;
    const int ww = w0 + 4 * tw;

    const float* in2b = in2 + (size_t)b * Cdim * HWs;

    // ---- per-thread staging descriptors (loop-invariant; computed once) ----
    // segment j handles float4 #(tid + j*NT) of the 1280 per chunk
    const float* sptr0; const float* sptr1; const float* sptr2;
    int soff0, soff1, soff2;
    bool sval0, sval1, sval2;
    auto mkseg = [&](int idx, const float*& p, int& off, bool& val) {
        const int cc  = idx / 160;            // 160 = HALO_H * 10 segs/row-block
        const int rem = idx - cc * 160;
        const int ry  = rem / 10;
        const int k   = rem - ry * 10;
        const int gr  = h0 - RADIUS + ry;
        const int gc0 = w0 - RADIUS + 4 * k;  // 16B aligned; float4 fully in or out
        val = ((unsigned)gr < (unsigned)Hdim) && ((unsigned)gc0 < (unsigned)Wdim);
        p   = in2b + (size_t)cc * HWs + (ptrdiff_t)(gr * Wdim + gc0);
        off = (cc * HALO_H + ry) * HALO_WP + 4 * k;
    };
    mkseg(tid,      sptr0, soff0, sval0);
    mkseg(tid + NT, sptr1, soff1, sval1);
    const bool act2 = tid < (NSEG - 2 * NT);  // 1280 - 1152 = 128 threads
    mkseg(act2 ? tid + 2 * NT : 0, sptr2, soff2, sval2);
    sval2 = sval2 && act2;

    float* sw = &s2[0][0][0][0];

    // ---- prologue: stage chunk 0 into buffer 0 ----
    {
        float4 v0 = {0.f,0.f,0.f,0.f}, v1 = {0.f,0.f,0.f,0.f}, v2 = {0.f,0.f,0.f,0.f};
        if (sval0) v0 = *(const float4*)sptr0;
        if (sval1) v1 = *(const float4*)sptr1;
        if (sval2) v2 = *(const float4*)sptr2;
        sptr0 += (size_t)CK * HWs; sptr1 += (size_t)CK * HWs; sptr2 += (size_t)CK * HWs;
        *(float4*)(sw + soff0) = v0;
        *(float4*)(sw + soff1) = v1;
        if (act2) *(float4*)(sw + soff2) = v2;
    }

    // in1 pipeline: A0 = channel ch, A1 = channel ch+1
    const float* p1 = in1 + (size_t)b * Cdim * HWs + (size_t)hh * Wdim + ww;
    float4 A0 = *(const float4*)(p1);
    float4 A1 = *(const float4*)(p1 + HWs);

    float acc[PSZ][4];
#pragma unroll
    for (int d = 0; d < PSZ; ++d)
#pragma unroll
        for (int j = 0; j < 4; ++j) acc[d][j] = 0.f;

    __syncthreads();

    const int rbase = (th + dh) * HALO_WP + 4 * tw;
    int cur = 0;
#pragma unroll 2
    for (int c = 0; c < NCHUNK; ++c) {
        // ---- issue next chunk's global loads early (latency hides under FMAs) ----
        float4 r0 = {0.f,0.f,0.f,0.f}, r1 = {0.f,0.f,0.f,0.f}, r2 = {0.f,0.f,0.f,0.f};
        const bool more = (c + 1 < NCHUNK);
        if (more) {
            if (sval0) r0 = *(const float4*)sptr0;
            if (sval1) r1 = *(const float4*)sptr1;
            if (sval2) r2 = *(const float4*)sptr2;
            sptr0 += (size_t)CK * HWs; sptr1 += (size_t)CK * HWs; sptr2 += (size_t)CK * HWs;
        }

        // ---- compute chunk c from s2[cur]: 36 FMAs + 3 ds_read_b128 per channel ----
        const float* sb = sw + cur * BUF_FLOATS;
#pragma unroll
        for (int cc = 0; cc < CK; ++cc) {
            const float a0 = A0.x, a1 = A0.y, a2 = A0.z, a3 = A0.w;
            A0 = A1;
            const int gch = c * CK + cc + 2;          // prefetch in1 two channels ahead
            if (gch < Cdim) A1 = *(const float4*)(p1 + (size_t)gch * HWs);

            const float* rowp = sb + cc * (HALO_H * HALO_WP) + rbase;
            const float4 wa = *(const float4*)(rowp);
            const float4 wb = *(const float4*)(rowp + 4);
            const float4 wc = *(const float4*)(rowp + 8);
            const float win[12] = {wa.x, wa.y, wa.z, wa.w,
                                   wb.x, wb.y, wb.z, wb.w,
                                   wc.x, wc.y, wc.z, wc.w};
#pragma unroll
            for (int dw = 0; dw < PSZ; ++dw) {
                acc[dw][0] = fmaf(a0, win[dw + 0], acc[dw][0]);
                acc[dw][1] = fmaf(a1, win[dw + 1], acc[dw][1]);
                acc[dw][2] = fmaf(a2, win[dw + 2], acc[dw][2]);
                acc[dw][3] = fmaf(a3, win[dw + 3], acc[dw][3]);
            }
        }

        // ---- write staged data to the other buffer; one barrier per chunk ----
        if (more) {
            float* dst = sw + (cur ^ 1) * BUF_FLOATS;
            *(float4*)(dst + soff0) = r0;
            *(float4*)(dst + soff1) = r1;
            if (act2) *(float4*)(dst + soff2) = r2;
            __syncthreads();
        }
        cur ^= 1;
    }

    // ---- epilogue: 9 float4 stores per thread ----
    const float scale = 1.0f / (float)Cdim;
    float* outp = out + (((size_t)(b * NP + dh * PSZ) * Hdim + hh) * Wdim + ww);
#pragma unroll
    for (int dw = 0; dw < PSZ; ++dw) {
        float4 o;
        o.x = acc[dw][0] * scale;
        o.y = acc[dw][1] * scale;
        o.z = acc[dw][2] * scale;
        o.w = acc[dw][3] * scale;
        *(float4*)(outp + (size_t)dw * HWs) = o;
    }
}

extern "C" void kernel_launch(void* const* d_in, const int* in_sizes, int n_in,
                              void* d_out, int out_size, void* d_ws, size_t ws_size,
                              hipStream_t stream)
{
    const float* in1 = (const float*)d_in[0];
    const float* in2 = (const float*)d_in[1];
    float* out = (float*)d_out;
    dim3 grid(Wdim / TW, Hdim / TH, Bdim);
    corr81<<<grid, NT, 0, stream>>>(in1, in2, out);
}